// Round 6
// baseline (1240.566 us; speedup 1.0000x reference)
//
#include <hip/hip_runtime.h>
#include <hip/hip_bf16.h>

// ---------------------------------------------------------------------------
// GraphSAGE distance estimator, fp32.
//   CSR build (both graphs batched): LDS bucket hist -> scan -> bucket-grouped
//   scatter -> per-bucket LDS counting sort (pow2 bucket width, no int div).
//   Per layer: {Y,R} = x@{Wl,Wr} in ONE fused zero-LDS GEMM: x rows via
//   same-address vector loads (HW broadcast, vmcnt-pipelined), W via coalesced
//   per-lane dword loads (L1/L2-resident). H = relu(csr-mean(Y) + bl + R)
//   fused into the aggregate kernel.
//   Pool: 8 partial blocks per graph (binary search, no atomics), combined in
//   final_mlp.
// ---------------------------------------------------------------------------

#define NB    1024   // dst buckets (pow2)
#define EPB   16384  // edges per grouping block
#define BWMAX 128    // max nodes per bucket (LDS arrays in sort)
#define PP    8      // pool partials per graph

// ---- CSR build (batched over both graphs) ----------------------------------

__global__ __launch_bounds__(256) void p1_hist(const int* __restrict__ dstS,
                                               const int* __restrict__ dstG,
                                               int* __restrict__ blkhist,
                                               int E, int bsh, int nblk) {
    const int g = blockIdx.x / nblk;
    const int blk = blockIdx.x % nblk;
    const int* __restrict__ dst = g ? dstG : dstS;
    __shared__ int h[NB];
    for (int i = threadIdx.x; i < NB; i += 256) h[i] = 0;
    __syncthreads();
    const int base = blk * EPB;
    for (int k = 0; k < EPB; k += 256) {
        const int e = base + k + threadIdx.x;
        if (e < E) atomicAdd(&h[dst[e] >> bsh], 1);
    }
    __syncthreads();
    for (int i = threadIdx.x; i < NB; i += 256)
        blkhist[((size_t)(g * nblk + blk)) * NB + i] = h[i];
}

__global__ __launch_bounds__(NB) void p1_scan(const int* __restrict__ blkhist,
                                              int* __restrict__ basem,
                                              int* __restrict__ bucket_base,
                                              int nblk) {
    __shared__ int lds[NB];
    const int g = blockIdx.x;
    const int* __restrict__ bh = blkhist + (size_t)g * nblk * NB;
    int* __restrict__ bm = basem + (size_t)g * nblk * NB;
    int* __restrict__ bb = bucket_base + (size_t)g * (NB + 1);
    const int b = threadIdx.x;
    int s = 0;
    for (int k = 0; k < nblk; ++k) s += bh[(size_t)k * NB + b];
    lds[b] = s;
    __syncthreads();
    for (int off = 1; off < NB; off <<= 1) {
        int v = (b >= off) ? lds[b - off] : 0;
        __syncthreads();
        lds[b] += v;
        __syncthreads();
    }
    int run = lds[b] - s;  // exclusive prefix
    bb[b] = run;
    if (b == NB - 1) bb[NB] = run + s;
    for (int k = 0; k < nblk; ++k) {
        const int c = bh[(size_t)k * NB + b];
        bm[(size_t)k * NB + b] = run;
        run += c;
    }
}

__global__ __launch_bounds__(256) void p1_scatter(const int* __restrict__ eiS,
                                                  const int* __restrict__ eiG,
                                                  const int* __restrict__ basem,
                                                  int2* __restrict__ pairs,
                                                  int E, int bsh, int nblk) {
    const int g = blockIdx.x / nblk;
    const int blk = blockIdx.x % nblk;
    const int* __restrict__ src = g ? eiG : eiS;
    const int* __restrict__ dst = src + E;
    int2* __restrict__ pr = pairs + (size_t)g * E;
    __shared__ int cur[NB];
    for (int i = threadIdx.x; i < NB; i += 256)
        cur[i] = basem[((size_t)(g * nblk + blk)) * NB + i];
    __syncthreads();
    const int base = blk * EPB;
    for (int k = 0; k < EPB; k += 256) {
        const int e = base + k + threadIdx.x;
        if (e < E) {
            const int d = dst[e];
            const int s = src[e];
            const int p = atomicAdd(&cur[d >> bsh], 1);
            pr[p] = make_int2(s, d);
        }
    }
}

__global__ __launch_bounds__(512) void p2_sort(const int2* __restrict__ pairs,
                                               const int* __restrict__ bucket_base,
                                               int* __restrict__ csr,
                                               int* __restrict__ row_start,
                                               int N, int E, int bsh) {
    __shared__ int cnt[BWMAX];
    __shared__ int off[BWMAX];
    const int g = blockIdx.x / NB;
    const int b = blockIdx.x % NB;
    const int bw = 1 << bsh;
    const int lo = b * bw;
    int nn = N - lo;
    if (nn <= 0) return;
    if (nn > bw) nn = bw;
    const int2* __restrict__ pr = pairs + (size_t)g * E;
    const int* __restrict__ bb = bucket_base + (size_t)g * (NB + 1);
    int* __restrict__ cs = csr + (size_t)g * E;
    int* __restrict__ rs = row_start + (size_t)g * (N + 1);
    const int tid = threadIdx.x;
    for (int i = tid; i < nn; i += 512) cnt[i] = 0;
    __syncthreads();
    const int e0 = bb[b];
    const int e1 = bb[b + 1];
    for (int e = e0 + tid; e < e1; e += 512)
        atomicAdd(&cnt[pr[e].y - lo], 1);
    __syncthreads();
    if (tid == 0) {
        int run = e0;
        for (int i = 0; i < nn; ++i) { off[i] = run; run += cnt[i]; }
    }
    __syncthreads();
    for (int i = tid; i < nn; i += 512) {
        rs[lo + i] = off[i];
        cnt[i] = off[i];  // reuse as cursor
    }
    if (lo + nn == N && tid == 0) rs[N] = e1;
    __syncthreads();
    for (int e = e0 + tid; e < e1; e += 512) {
        const int2 p = pr[e];
        const int pos = atomicAdd(&cnt[p.y - lo], 1);
        cs[pos] = p.x;
    }
}

// ---- fused dual-weight GEMM: Y = x@Wl, R = x@Wr (zero LDS) ------------------
// 4 waves x 8 rows. x rows: per-lane float4 loads with identical address
// within a wave (threadIdx-derived base keeps them vector loads; coalescer
// broadcasts a single line fetch). W: coalesced per-lane dword loads, L1/L2
// resident (reused by every block). Everything rides vmcnt -> deep pipeline.
template <int K>
__global__ __launch_bounds__(256) void gemm_fused(const float* __restrict__ x,
                                                  const float* __restrict__ Wl,
                                                  const float* __restrict__ Wr,
                                                  float* __restrict__ Y,
                                                  float* __restrict__ R, int n) {
    const int tid = threadIdx.x;
    const int lane = tid & 63;
    const int wid = tid >> 6;                    // no readfirstlane: keep vector loads
    const int rbase = blockIdx.x * 32 + wid * 8;
    const float* xr[8];
    #pragma unroll
    for (int r = 0; r < 8; ++r) {
        int row = rbase + r;
        if (row > n - 1) row = n - 1;
        xr[r] = x + (size_t)row * K;
    }
    float accY[8], accR[8];
    #pragma unroll
    for (int r = 0; r < 8; ++r) { accY[r] = 0.f; accR[r] = 0.f; }

    #pragma unroll 2
    for (int k4 = 0; k4 < K / 4; ++k4) {
        float wl[4], wr[4];
        #pragma unroll
        for (int t = 0; t < 4; ++t) {
            wl[t] = Wl[(k4 * 4 + t) * 64 + lane];
            wr[t] = Wr[(k4 * 4 + t) * 64 + lane];
        }
        #pragma unroll
        for (int r = 0; r < 8; ++r) {
            const float4 xv = *(const float4*)(xr[r] + k4 * 4);
            accY[r] += xv.x * wl[0] + xv.y * wl[1] + xv.z * wl[2] + xv.w * wl[3];
            accR[r] += xv.x * wr[0] + xv.y * wr[1] + xv.z * wr[2] + xv.w * wr[3];
        }
    }
    #pragma unroll
    for (int r = 0; r < 8; ++r) {
        const int row = rbase + r;
        if (row < n) {
            Y[(size_t)row * 64 + lane] = accY[r];
            R[(size_t)row * 64 + lane] = accR[r];
        }
    }
}

// ---- aggregate + epilogue: H = relu(mean_csr(Y) + bl + R) -------------------
__global__ __launch_bounds__(256) void agg_fused(const float* __restrict__ Y,
                                                 const float* __restrict__ R,
                                                 const float* __restrict__ bl,
                                                 const int* __restrict__ csr,
                                                 const int* __restrict__ row_start,
                                                 float* __restrict__ H, int n) {
    const int wid = threadIdx.x >> 6;
    const int lane = threadIdx.x & 63;
    const int i = blockIdx.x * 4 + wid;
    if (i >= n) return;
    const int r0 = __builtin_amdgcn_readfirstlane(row_start[i]);
    const int r1 = __builtin_amdgcn_readfirstlane(row_start[i + 1]);
    float a[16];
    #pragma unroll
    for (int t = 0; t < 16; ++t) a[t] = 0.f;
    int e = r0;
    for (; e + 16 <= r1; e += 16) {
        #pragma unroll
        for (int t = 0; t < 16; ++t)
            a[t] += Y[(size_t)csr[e + t] * 64 + lane];
    }
    for (; e < r1; ++e) a[0] += Y[(size_t)csr[e] * 64 + lane];
    float acc = 0.f;
    #pragma unroll
    for (int t = 0; t < 16; ++t) acc += a[t];
    const int c = r1 - r0;
    const float sc = (c > 0) ? (1.0f / (float)c) : 1.0f;
    const float v = acc * sc + bl[lane] + R[(size_t)i * 64 + lane];
    H[(size_t)i * 64 + lane] = fmaxf(v, 0.0f);
}

// ---- pooling: PP partial blocks per graph (sorted batch, binary search) -----
__global__ __launch_bounds__(256) void pool_part(const float* __restrict__ H,
                                                 const int* __restrict__ batch,
                                                 float* __restrict__ parts,
                                                 int* __restrict__ pcnt, int n) {
    const int b = blockIdx.x / PP;
    const int p = blockIdx.x % PP;
    int lo = 0, hi = n;
    while (lo < hi) { int m = (lo + hi) >> 1; if (batch[m] < b) lo = m + 1; else hi = m; }
    const int beg = lo;
    hi = n;
    while (lo < hi) { int m = (lo + hi) >> 1; if (batch[m] < b + 1) lo = m + 1; else hi = m; }
    const int end = lo;
    const int len = end - beg;
    const int chunk = (len + PP - 1) / PP;
    const int s0 = beg + p * chunk;
    int s1 = s0 + chunk; if (s1 > end) s1 = end;

    const int wid = threadIdx.x >> 6;
    const int lane = threadIdx.x & 63;
    float acc = 0.f;
    for (int i = s0 + wid; i < s1; i += 4)
        acc += H[(size_t)i * 64 + lane];
    __shared__ float part[4][64];
    part[wid][lane] = acc;
    __syncthreads();
    if (wid == 0) {
        const float s = (part[0][lane] + part[1][lane]) + (part[2][lane] + part[3][lane]);
        parts[(size_t)(b * PP + p) * 64 + lane] = s;
        if (lane == 0 && p == 0) pcnt[b] = len;
    }
}

__global__ __launch_bounds__(128) void final_mlp(const float* __restrict__ partsS,
                                                 const int* __restrict__ cntS,
                                                 const float* __restrict__ partsG,
                                                 const int* __restrict__ cntG,
                                                 const float* __restrict__ depth,
                                                 const float* __restrict__ W1,
                                                 const float* __restrict__ b1,
                                                 const float* __restrict__ W2,
                                                 const float* __restrict__ b2,
                                                 float* __restrict__ out, int Bn) {
    __shared__ float lW1[129 * 64];
    __shared__ float red[128];
    const int t = threadIdx.x;
    for (int i = t; i < 129 * 64; i += 128) lW1[i] = W1[i];
    const float d = (t < Bn) ? depth[t] : 0.0f;
    red[t] = d;
    __syncthreads();
    for (int off = 64; off > 0; off >>= 1) {
        if (t < off) red[t] += red[t + off];
        __syncthreads();
    }
    const float mean = red[0] / (float)Bn;
    __syncthreads();
    const float dev = d - mean;
    red[t] = (t < Bn) ? dev * dev : 0.0f;
    __syncthreads();
    for (int off = 64; off > 0; off >>= 1) {
        if (t < off) red[t] += red[t + off];
        __syncthreads();
    }
    const float stdv = sqrtf(red[0] / (float)Bn);
    const float dn = dev / (stdv + 1e-6f);
    if (t >= Bn) return;

    float acc[64];
    #pragma unroll
    for (int j = 0; j < 64; ++j) acc[j] = b1[j];
    int cs = cntS[t]; if (cs < 1) cs = 1;
    int cg = cntG[t]; if (cg < 1) cg = 1;
    const float invS = 1.0f / (float)cs;
    const float invG = 1.0f / (float)cg;
    for (int k = 0; k < 64; ++k) {
        float fk = 0.f;
        #pragma unroll
        for (int p = 0; p < PP; ++p) fk += partsS[(size_t)(t * PP + p) * 64 + k];
        fk *= invS;
        #pragma unroll
        for (int j = 0; j < 64; ++j) acc[j] += fk * lW1[k * 64 + j];
    }
    for (int k = 0; k < 64; ++k) {
        float fk = 0.f;
        #pragma unroll
        for (int p = 0; p < PP; ++p) fk += partsG[(size_t)(t * PP + p) * 64 + k];
        fk *= invG;
        #pragma unroll
        for (int j = 0; j < 64; ++j) acc[j] += fk * lW1[(64 + k) * 64 + j];
    }
    #pragma unroll
    for (int j = 0; j < 64; ++j) acc[j] += dn * lW1[128 * 64 + j];
    float o = b2[0];
    #pragma unroll
    for (int j = 0; j < 64; ++j) o += fmaxf(acc[j], 0.0f) * W2[j];
    out[t] = o;
}

extern "C" void kernel_launch(void* const* d_in, const int* in_sizes, int n_in,
                              void* d_out, int out_size, void* d_ws, size_t ws_size,
                              hipStream_t stream) {
    const float* state_x     = (const float*)d_in[0];
    const int*   state_ei    = (const int*)d_in[1];
    const int*   state_batch = (const int*)d_in[2];
    const float* goal_x      = (const float*)d_in[3];
    const int*   goal_ei     = (const int*)d_in[4];
    const int*   goal_batch  = (const int*)d_in[5];
    const float* depth       = (const float*)d_in[6];
    const float* s1_Wl = (const float*)d_in[7];
    const float* s1_bl = (const float*)d_in[8];
    const float* s1_Wr = (const float*)d_in[9];
    const float* s2_Wl = (const float*)d_in[10];
    const float* s2_bl = (const float*)d_in[11];
    const float* s2_Wr = (const float*)d_in[12];
    const float* g1_Wl = (const float*)d_in[13];
    const float* g1_bl = (const float*)d_in[14];
    const float* g1_Wr = (const float*)d_in[15];
    const float* g2_Wl = (const float*)d_in[16];
    const float* g2_bl = (const float*)d_in[17];
    const float* g2_Wr = (const float*)d_in[18];
    const float* mlp_W1 = (const float*)d_in[19];
    const float* mlp_b1 = (const float*)d_in[20];
    const float* mlp_W2 = (const float*)d_in[21];
    const float* mlp_b2 = (const float*)d_in[22];

    const int N  = in_sizes[0] / 128;
    const int E  = in_sizes[1] / 2;
    const int Bn = in_sizes[6];
    const int nblk = (E + EPB - 1) / EPB;
    int bsh = 0;
    while (((size_t)NB << bsh) < (size_t)N) ++bsh;  // bucket width 2^bsh

    char* w = (char*)d_ws;
    auto alloc = [&](size_t bytes) {
        char* p = w;
        w += (bytes + 255) & ~(size_t)255;
        return p;
    };
    float* bufY        = (float*)alloc((size_t)N * 64 * sizeof(float));
    float* bufR        = (float*)alloc((size_t)N * 64 * sizeof(float));
    float* bufH        = (float*)alloc((size_t)N * 64 * sizeof(float));
    int*   csr         = (int*)alloc((size_t)2 * E * sizeof(int));
    int*   row_start   = (int*)alloc((size_t)2 * (N + 1) * sizeof(int));
    int*   blkhist     = (int*)alloc((size_t)2 * nblk * NB * sizeof(int));
    int*   basem       = (int*)alloc((size_t)2 * nblk * NB * sizeof(int));
    int*   bucket_base = (int*)alloc((size_t)2 * (NB + 1) * sizeof(int));
    float* partsS      = (float*)alloc((size_t)Bn * PP * 64 * sizeof(float));
    float* partsG      = (float*)alloc((size_t)Bn * PP * 64 * sizeof(float));
    int*   cntS        = (int*)alloc((size_t)Bn * sizeof(int));
    int*   cntG        = (int*)alloc((size_t)Bn * sizeof(int));
    int2*  pairs       = (int2*)bufY;  // aliases bufY+bufR (dead during CSR build)
    const size_t need = (size_t)(w - (char*)d_ws);
    const bool pairs_fit = (size_t)2 * E * sizeof(int2) <= (size_t)2 * N * 64 * sizeof(float);
    if (need > ws_size || (1 << bsh) > BWMAX || !pairs_fit) {
        hipMemsetAsync(d_out, 0, (size_t)out_size * sizeof(float), stream);
        return;
    }

    // ---- CSR build, both graphs ----
    p1_hist<<<2 * nblk, 256, 0, stream>>>(state_ei + E, goal_ei + E, blkhist, E, bsh, nblk);
    p1_scan<<<2, NB, 0, stream>>>(blkhist, basem, bucket_base, nblk);
    p1_scatter<<<2 * nblk, 256, 0, stream>>>(state_ei, goal_ei, basem, pairs, E, bsh, nblk);
    p2_sort<<<2 * NB, 512, 0, stream>>>(pairs, bucket_base, csr, row_start, N, E, bsh);

    const int g32 = (N + 31) / 32;
    const int g4  = (N + 3) / 4;
    const int* csrS = csr;
    const int* csrG = csr + E;
    const int* rsS  = row_start;
    const int* rsG  = row_start + (N + 1);

    // ---- state encoder ----
    gemm_fused<128><<<g32, 256, 0, stream>>>(state_x, s1_Wl, s1_Wr, bufY, bufR, N);
    agg_fused<<<g4, 256, 0, stream>>>(bufY, bufR, s1_bl, csrS, rsS, bufH, N);
    gemm_fused<64><<<g32, 256, 0, stream>>>(bufH, s2_Wl, s2_Wr, bufY, bufR, N);
    agg_fused<<<g4, 256, 0, stream>>>(bufY, bufR, s2_bl, csrS, rsS, bufH, N);
    pool_part<<<Bn * PP, 256, 0, stream>>>(bufH, state_batch, partsS, cntS, N);

    // ---- goal encoder ----
    gemm_fused<128><<<g32, 256, 0, stream>>>(goal_x, g1_Wl, g1_Wr, bufY, bufR, N);
    agg_fused<<<g4, 256, 0, stream>>>(bufY, bufR, g1_bl, csrG, rsG, bufH, N);
    gemm_fused<64><<<g32, 256, 0, stream>>>(bufH, g2_Wl, g2_Wr, bufY, bufR, N);
    agg_fused<<<g4, 256, 0, stream>>>(bufY, bufR, g2_bl, csrG, rsG, bufH, N);
    pool_part<<<Bn * PP, 256, 0, stream>>>(bufH, goal_batch, partsG, cntG, N);

    final_mlp<<<1, 128, 0, stream>>>(partsS, cntS, partsG, cntG, depth,
                                     mlp_W1, mlp_b1, mlp_W2, mlp_b2, (float*)d_out, Bn);
}

// Round 7
// 1150.713 us; speedup vs baseline: 1.0781x; 1.0781x over previous
//
#include <hip/hip_runtime.h>
#include <hip/hip_bf16.h>

// ---------------------------------------------------------------------------
// GraphSAGE distance estimator, fp32.
//   CSR build (both graphs batched): LDS bucket hist -> scan -> bucket-grouped
//   scatter of PACKED (src | dlocal<<17) ints -> per-bucket LDS counting sort
//   into dst-sorted CSR (+row_start).
//   Per layer: {Y,R} = x@{Wl,Wr} in ONE fused GEMM: W pairs interleaved in LDS
//   (ds_read_b64, lgkmcnt), x rows via same-address per-lane float4 global
//   loads (vmcnt) -> the two pipes overlap; 512-thr blocks for occupancy.
//   H = relu(csr-mean(Y) + bl + R) fused into the aggregate kernel.
//   Pool: 8 partial blocks per graph (binary search, no atomics) -> final_mlp.
// ---------------------------------------------------------------------------

#define NB    1024   // dst buckets (pow2)
#define EPB   16384  // edges per grouping block
#define BWMAX 128    // max nodes per bucket (LDS arrays in sort)
#define PP    8      // pool partials per graph
#define SRCB  17     // bits for src id in packed pair (N <= 131072)

// ---- CSR build (batched over both graphs) ----------------------------------

__global__ __launch_bounds__(256) void p1_hist(const int* __restrict__ dstS,
                                               const int* __restrict__ dstG,
                                               int* __restrict__ blkhist,
                                               int E, int bsh, int nblk) {
    const int g = blockIdx.x / nblk;
    const int blk = blockIdx.x % nblk;
    const int* __restrict__ dst = g ? dstG : dstS;
    __shared__ int h[NB];
    for (int i = threadIdx.x; i < NB; i += 256) h[i] = 0;
    __syncthreads();
    const int base = blk * EPB;
    for (int k = 0; k < EPB; k += 256) {
        const int e = base + k + threadIdx.x;
        if (e < E) atomicAdd(&h[dst[e] >> bsh], 1);
    }
    __syncthreads();
    for (int i = threadIdx.x; i < NB; i += 256)
        blkhist[((size_t)(g * nblk + blk)) * NB + i] = h[i];
}

__global__ __launch_bounds__(NB) void p1_scan(const int* __restrict__ blkhist,
                                              int* __restrict__ basem,
                                              int* __restrict__ bucket_base,
                                              int nblk) {
    __shared__ int lds[NB];
    const int g = blockIdx.x;
    const int* __restrict__ bh = blkhist + (size_t)g * nblk * NB;
    int* __restrict__ bm = basem + (size_t)g * nblk * NB;
    int* __restrict__ bb = bucket_base + (size_t)g * (NB + 1);
    const int b = threadIdx.x;
    int s = 0;
    for (int k = 0; k < nblk; ++k) s += bh[(size_t)k * NB + b];
    lds[b] = s;
    __syncthreads();
    for (int off = 1; off < NB; off <<= 1) {
        int v = (b >= off) ? lds[b - off] : 0;
        __syncthreads();
        lds[b] += v;
        __syncthreads();
    }
    int run = lds[b] - s;  // exclusive prefix
    bb[b] = run;
    if (b == NB - 1) bb[NB] = run + s;
    for (int k = 0; k < nblk; ++k) {
        const int c = bh[(size_t)k * NB + b];
        bm[(size_t)k * NB + b] = run;
        run += c;
    }
}

__global__ __launch_bounds__(256) void p1_scatter(const int* __restrict__ eiS,
                                                  const int* __restrict__ eiG,
                                                  const int* __restrict__ basem,
                                                  int* __restrict__ pairs,
                                                  int E, int bsh, int nblk) {
    const int g = blockIdx.x / nblk;
    const int blk = blockIdx.x % nblk;
    const int* __restrict__ src = g ? eiG : eiS;
    const int* __restrict__ dst = src + E;
    int* __restrict__ pr = pairs + (size_t)g * E;
    const int bwm = (1 << bsh) - 1;
    __shared__ int cur[NB];
    for (int i = threadIdx.x; i < NB; i += 256)
        cur[i] = basem[((size_t)(g * nblk + blk)) * NB + i];
    __syncthreads();
    const int base = blk * EPB;
    for (int k = 0; k < EPB; k += 256) {
        const int e = base + k + threadIdx.x;
        if (e < E) {
            const int d = dst[e];
            const int s = src[e];
            const int p = atomicAdd(&cur[d >> bsh], 1);
            pr[p] = s | ((d & bwm) << SRCB);   // packed: src(17b) | dlocal(<=15b)
        }
    }
}

__global__ __launch_bounds__(512) void p2_sort(const int* __restrict__ pairs,
                                               const int* __restrict__ bucket_base,
                                               int* __restrict__ csr,
                                               int* __restrict__ row_start,
                                               int N, int E, int bsh) {
    __shared__ int cnt[BWMAX];
    __shared__ int off[BWMAX];
    const int g = blockIdx.x / NB;
    const int b = blockIdx.x % NB;
    const int bw = 1 << bsh;
    const int lo = b * bw;
    int nn = N - lo;
    if (nn <= 0) return;
    if (nn > bw) nn = bw;
    const int* __restrict__ pr = pairs + (size_t)g * E;
    const int* __restrict__ bb = bucket_base + (size_t)g * (NB + 1);
    int* __restrict__ cs = csr + (size_t)g * E;
    int* __restrict__ rs = row_start + (size_t)g * (N + 1);
    const int tid = threadIdx.x;
    for (int i = tid; i < nn; i += 512) cnt[i] = 0;
    __syncthreads();
    const int e0 = bb[b];
    const int e1 = bb[b + 1];
    for (int e = e0 + tid; e < e1; e += 512)
        atomicAdd(&cnt[pr[e] >> SRCB], 1);
    __syncthreads();
    if (tid == 0) {
        int run = e0;
        for (int i = 0; i < nn; ++i) { off[i] = run; run += cnt[i]; }
    }
    __syncthreads();
    for (int i = tid; i < nn; i += 512) {
        rs[lo + i] = off[i];
        cnt[i] = off[i];  // reuse as cursor
    }
    if (lo + nn == N && tid == 0) rs[N] = e1;
    __syncthreads();
    for (int e = e0 + tid; e < e1; e += 512) {
        const int v = pr[e];
        const int pos = atomicAdd(&cnt[v >> SRCB], 1);
        cs[pos] = v & ((1 << SRCB) - 1);
    }
}

// ---- fused dual-weight GEMM: Y = x@Wl, R = x@Wr -----------------------------
// 512 thr = 8 waves x 8 rows. W as interleaved (wl,wr) float2 in LDS
// (ds_read_b64 -> lgkmcnt); x rows as same-address per-lane float4 global
// loads (vmcnt). The two counters pipeline independently; VALU-bound core.
template <int K>
__global__ __launch_bounds__(512) void gemm_fused(const float* __restrict__ x,
                                                  const float* __restrict__ Wl,
                                                  const float* __restrict__ Wr,
                                                  float* __restrict__ Y,
                                                  float* __restrict__ R, int n) {
    __shared__ float2 ldsW[K * 64];
    const int tid = threadIdx.x;
    const int lane = tid & 63;
    const int wid = tid >> 6;
    for (int i = tid; i < K * 64; i += 512)
        ldsW[i] = make_float2(Wl[i], Wr[i]);
    __syncthreads();

    const int rbase = blockIdx.x * 64 + wid * 8;
    const float* xr[8];
    #pragma unroll
    for (int r = 0; r < 8; ++r) {
        int row = rbase + r;
        if (row > n - 1) row = n - 1;
        xr[r] = x + (size_t)row * K;
    }
    float accY[8], accR[8];
    #pragma unroll
    for (int r = 0; r < 8; ++r) { accY[r] = 0.f; accR[r] = 0.f; }

    #pragma unroll 2
    for (int k4 = 0; k4 < K / 4; ++k4) {
        float2 w[4];
        #pragma unroll
        for (int t = 0; t < 4; ++t)
            w[t] = ldsW[(k4 * 4 + t) * 64 + lane];
        #pragma unroll
        for (int r = 0; r < 8; ++r) {
            const float4 xv = *(const float4*)(xr[r] + k4 * 4);
            accY[r] += xv.x * w[0].x + xv.y * w[1].x + xv.z * w[2].x + xv.w * w[3].x;
            accR[r] += xv.x * w[0].y + xv.y * w[1].y + xv.z * w[2].y + xv.w * w[3].y;
        }
    }
    #pragma unroll
    for (int r = 0; r < 8; ++r) {
        const int row = rbase + r;
        if (row < n) {
            Y[(size_t)row * 64 + lane] = accY[r];
            R[(size_t)row * 64 + lane] = accR[r];
        }
    }
}

// ---- aggregate + epilogue: H = relu(mean_csr(Y) + bl + R) -------------------
__global__ __launch_bounds__(256) void agg_fused(const float* __restrict__ Y,
                                                 const float* __restrict__ R,
                                                 const float* __restrict__ bl,
                                                 const int* __restrict__ csr,
                                                 const int* __restrict__ row_start,
                                                 float* __restrict__ H, int n) {
    const int wid = threadIdx.x >> 6;
    const int lane = threadIdx.x & 63;
    const int i = blockIdx.x * 4 + wid;
    if (i >= n) return;
    const int r0 = __builtin_amdgcn_readfirstlane(row_start[i]);
    const int r1 = __builtin_amdgcn_readfirstlane(row_start[i + 1]);
    float a[16];
    #pragma unroll
    for (int t = 0; t < 16; ++t) a[t] = 0.f;
    int e = r0;
    for (; e + 16 <= r1; e += 16) {
        #pragma unroll
        for (int t = 0; t < 16; ++t)
            a[t] += Y[(size_t)csr[e + t] * 64 + lane];
    }
    for (; e < r1; ++e) a[0] += Y[(size_t)csr[e] * 64 + lane];
    float acc = 0.f;
    #pragma unroll
    for (int t = 0; t < 16; ++t) acc += a[t];
    const int c = r1 - r0;
    const float sc = (c > 0) ? (1.0f / (float)c) : 1.0f;
    const float v = acc * sc + bl[lane] + R[(size_t)i * 64 + lane];
    H[(size_t)i * 64 + lane] = fmaxf(v, 0.0f);
}

// ---- pooling: PP partial blocks per graph (sorted batch, binary search) -----
__global__ __launch_bounds__(256) void pool_part(const float* __restrict__ H,
                                                 const int* __restrict__ batch,
                                                 float* __restrict__ parts,
                                                 int* __restrict__ pcnt, int n) {
    const int b = blockIdx.x / PP;
    const int p = blockIdx.x % PP;
    int lo = 0, hi = n;
    while (lo < hi) { int m = (lo + hi) >> 1; if (batch[m] < b) lo = m + 1; else hi = m; }
    const int beg = lo;
    hi = n;
    while (lo < hi) { int m = (lo + hi) >> 1; if (batch[m] < b + 1) lo = m + 1; else hi = m; }
    const int end = lo;
    const int len = end - beg;
    const int chunk = (len + PP - 1) / PP;
    const int s0 = beg + p * chunk;
    int s1 = s0 + chunk; if (s1 > end) s1 = end;

    const int wid = threadIdx.x >> 6;
    const int lane = threadIdx.x & 63;
    float acc = 0.f;
    for (int i = s0 + wid; i < s1; i += 4)
        acc += H[(size_t)i * 64 + lane];
    __shared__ float part[4][64];
    part[wid][lane] = acc;
    __syncthreads();
    if (wid == 0) {
        const float s = (part[0][lane] + part[1][lane]) + (part[2][lane] + part[3][lane]);
        parts[(size_t)(b * PP + p) * 64 + lane] = s;
        if (lane == 0 && p == 0) pcnt[b] = len;
    }
}

__global__ __launch_bounds__(128) void final_mlp(const float* __restrict__ partsS,
                                                 const int* __restrict__ cntS,
                                                 const float* __restrict__ partsG,
                                                 const int* __restrict__ cntG,
                                                 const float* __restrict__ depth,
                                                 const float* __restrict__ W1,
                                                 const float* __restrict__ b1,
                                                 const float* __restrict__ W2,
                                                 const float* __restrict__ b2,
                                                 float* __restrict__ out, int Bn) {
    __shared__ float lW1[129 * 64];
    __shared__ float red[128];
    const int t = threadIdx.x;
    for (int i = t; i < 129 * 64; i += 128) lW1[i] = W1[i];
    const float d = (t < Bn) ? depth[t] : 0.0f;
    red[t] = d;
    __syncthreads();
    for (int off = 64; off > 0; off >>= 1) {
        if (t < off) red[t] += red[t + off];
        __syncthreads();
    }
    const float mean = red[0] / (float)Bn;
    __syncthreads();
    const float dev = d - mean;
    red[t] = (t < Bn) ? dev * dev : 0.0f;
    __syncthreads();
    for (int off = 64; off > 0; off >>= 1) {
        if (t < off) red[t] += red[t + off];
        __syncthreads();
    }
    const float stdv = sqrtf(red[0] / (float)Bn);
    const float dn = dev / (stdv + 1e-6f);
    if (t >= Bn) return;

    float acc[64];
    #pragma unroll
    for (int j = 0; j < 64; ++j) acc[j] = b1[j];
    int cs = cntS[t]; if (cs < 1) cs = 1;
    int cg = cntG[t]; if (cg < 1) cg = 1;
    const float invS = 1.0f / (float)cs;
    const float invG = 1.0f / (float)cg;
    for (int k = 0; k < 64; ++k) {
        float fk = 0.f;
        #pragma unroll
        for (int p = 0; p < PP; ++p) fk += partsS[(size_t)(t * PP + p) * 64 + k];
        fk *= invS;
        #pragma unroll
        for (int j = 0; j < 64; ++j) acc[j] += fk * lW1[k * 64 + j];
    }
    for (int k = 0; k < 64; ++k) {
        float fk = 0.f;
        #pragma unroll
        for (int p = 0; p < PP; ++p) fk += partsG[(size_t)(t * PP + p) * 64 + k];
        fk *= invG;
        #pragma unroll
        for (int j = 0; j < 64; ++j) acc[j] += fk * lW1[(64 + k) * 64 + j];
    }
    #pragma unroll
    for (int j = 0; j < 64; ++j) acc[j] += dn * lW1[128 * 64 + j];
    float o = b2[0];
    #pragma unroll
    for (int j = 0; j < 64; ++j) o += fmaxf(acc[j], 0.0f) * W2[j];
    out[t] = o;
}

extern "C" void kernel_launch(void* const* d_in, const int* in_sizes, int n_in,
                              void* d_out, int out_size, void* d_ws, size_t ws_size,
                              hipStream_t stream) {
    const float* state_x     = (const float*)d_in[0];
    const int*   state_ei    = (const int*)d_in[1];
    const int*   state_batch = (const int*)d_in[2];
    const float* goal_x      = (const float*)d_in[3];
    const int*   goal_ei     = (const int*)d_in[4];
    const int*   goal_batch  = (const int*)d_in[5];
    const float* depth       = (const float*)d_in[6];
    const float* s1_Wl = (const float*)d_in[7];
    const float* s1_bl = (const float*)d_in[8];
    const float* s1_Wr = (const float*)d_in[9];
    const float* s2_Wl = (const float*)d_in[10];
    const float* s2_bl = (const float*)d_in[11];
    const float* s2_Wr = (const float*)d_in[12];
    const float* g1_Wl = (const float*)d_in[13];
    const float* g1_bl = (const float*)d_in[14];
    const float* g1_Wr = (const float*)d_in[15];
    const float* g2_Wl = (const float*)d_in[16];
    const float* g2_bl = (const float*)d_in[17];
    const float* g2_Wr = (const float*)d_in[18];
    const float* mlp_W1 = (const float*)d_in[19];
    const float* mlp_b1 = (const float*)d_in[20];
    const float* mlp_W2 = (const float*)d_in[21];
    const float* mlp_b2 = (const float*)d_in[22];

    const int N  = in_sizes[0] / 128;
    const int E  = in_sizes[1] / 2;
    const int Bn = in_sizes[6];
    const int nblk = (E + EPB - 1) / EPB;
    int bsh = 0;
    while (((size_t)NB << bsh) < (size_t)N) ++bsh;  // bucket width 2^bsh

    char* w = (char*)d_ws;
    auto alloc = [&](size_t bytes) {
        char* p = w;
        w += (bytes + 255) & ~(size_t)255;
        return p;
    };
    float* bufY        = (float*)alloc((size_t)N * 64 * sizeof(float));
    float* bufR        = (float*)alloc((size_t)N * 64 * sizeof(float));
    float* bufH        = (float*)alloc((size_t)N * 64 * sizeof(float));
    int*   csr         = (int*)alloc((size_t)2 * E * sizeof(int));
    int*   row_start   = (int*)alloc((size_t)2 * (N + 1) * sizeof(int));
    int*   blkhist     = (int*)alloc((size_t)2 * nblk * NB * sizeof(int));
    int*   basem       = (int*)alloc((size_t)2 * nblk * NB * sizeof(int));
    int*   bucket_base = (int*)alloc((size_t)2 * (NB + 1) * sizeof(int));
    float* partsS      = (float*)alloc((size_t)Bn * PP * 64 * sizeof(float));
    float* partsG      = (float*)alloc((size_t)Bn * PP * 64 * sizeof(float));
    int*   cntS        = (int*)alloc((size_t)Bn * sizeof(int));
    int*   cntG        = (int*)alloc((size_t)Bn * sizeof(int));
    int*   pairs       = (int*)bufY;  // packed pairs alias bufY (dead in CSR build)
    const size_t need = (size_t)(w - (char*)d_ws);
    const bool pairs_fit = (size_t)2 * E * sizeof(int) <= (size_t)N * 64 * sizeof(float);
    if (need > ws_size || (1 << bsh) > BWMAX || !pairs_fit || N > (1 << SRCB)) {
        hipMemsetAsync(d_out, 0, (size_t)out_size * sizeof(float), stream);
        return;
    }

    // ---- CSR build, both graphs ----
    p1_hist<<<2 * nblk, 256, 0, stream>>>(state_ei + E, goal_ei + E, blkhist, E, bsh, nblk);
    p1_scan<<<2, NB, 0, stream>>>(blkhist, basem, bucket_base, nblk);
    p1_scatter<<<2 * nblk, 256, 0, stream>>>(state_ei, goal_ei, basem, pairs, E, bsh, nblk);
    p2_sort<<<2 * NB, 512, 0, stream>>>(pairs, bucket_base, csr, row_start, N, E, bsh);

    const int g64 = (N + 63) / 64;
    const int g4  = (N + 3) / 4;
    const int* csrS = csr;
    const int* csrG = csr + E;
    const int* rsS  = row_start;
    const int* rsG  = row_start + (N + 1);

    // ---- state encoder ----
    gemm_fused<128><<<g64, 512, 0, stream>>>(state_x, s1_Wl, s1_Wr, bufY, bufR, N);
    agg_fused<<<g4, 256, 0, stream>>>(bufY, bufR, s1_bl, csrS, rsS, bufH, N);
    gemm_fused<64><<<g64, 512, 0, stream>>>(bufH, s2_Wl, s2_Wr, bufY, bufR, N);
    agg_fused<<<g4, 256, 0, stream>>>(bufY, bufR, s2_bl, csrS, rsS, bufH, N);
    pool_part<<<Bn * PP, 256, 0, stream>>>(bufH, state_batch, partsS, cntS, N);

    // ---- goal encoder ----
    gemm_fused<128><<<g64, 512, 0, stream>>>(goal_x, g1_Wl, g1_Wr, bufY, bufR, N);
    agg_fused<<<g4, 256, 0, stream>>>(bufY, bufR, g1_bl, csrG, rsG, bufH, N);
    gemm_fused<64><<<g64, 512, 0, stream>>>(bufH, g2_Wl, g2_Wr, bufY, bufR, N);
    agg_fused<<<g4, 256, 0, stream>>>(bufY, bufR, g2_bl, csrG, rsG, bufH, N);
    pool_part<<<Bn * PP, 256, 0, stream>>>(bufH, goal_batch, partsG, cntG, N);

    final_mlp<<<1, 128, 0, stream>>>(partsS, cntS, partsG, cntG, depth,
                                     mlp_W1, mlp_b1, mlp_W2, mlp_b2, (float*)d_out, Bn);
}